// Round 6
// baseline (221.418 us; speedup 1.0000x reference)
//
#include <hip/hip_runtime.h>
#include <hip/hip_fp16.h>

// SparseEncoder4D: gather-GEMM-scatter sparse conv (1->8->8->1) + dense scatter.
// Slot model (R10-R12 confirmed): k_h2m cost ~ vmem lane-slots/wave x waves/CU.
// R12: 46.5 us @ ~2130 slots (idx staged dwordx4->LDS, Btab staged, bits uint4).
// Total 210 us with ~163 us in unmeasurable dispatches (top-5 saturated by
// k_h2m) -> launch overhead + h1b/scatters.
// R13: (a) exec-masked gathers: mask density 50%, masked lanes issue NOTHING
//          (gather slots 1344 -> ~700; sentinel scheme made all 64 issue).
//      (b) fuse k_scat_max into k_h1b (same shape; atomic hides under staging)
//          and k_scat_write into k_h2m epilogue (m==0 lanes hold the values);
//          outf deleted; 5 -> 3 dispatches.
// Predict k_h2m ~36 us, total ~170-180 us.
// NOTE: assumes n_total % 16 == 0 (holds: 150000).

#define KK 81
#define CH 8
#define NS 21     // K-slices of 32: ceil(648/32)
#define TT 4
#define ZZ 32
#define YY 256
#define XX 256

typedef __attribute__((ext_vector_type(8))) _Float16 half8;  // 16 B
typedef __attribute__((ext_vector_type(4))) float f32x4;

__device__ __forceinline__ int cell_of(const int* coords, const int* batch, int n) {
    int4 c = *(const int4*)(coords + 4 * n);  // (x, y, z, t)
    int b = batch[n];
    return (((b * TT + c.w) * ZZ + c.z) * YY + c.y) * XX + c.x;
}

// ---------------- layer 1 (feats==ones) + scat_max fusion -------------------
// h1 fp16, bits4[n]={w0,w1,w2,0} (81-bit mask LE), Btab (B-frags for k_h2m),
// and atomicMax winner-election into the dense grid (out as int).
__global__ __launch_bounds__(256) void k_h1b(const float* __restrict__ w1,
                                             const float* __restrict__ w2,
                                             const int* __restrict__ nbr_mask,
                                             const int* __restrict__ coords,
                                             const int* __restrict__ batch,
                                             half8* __restrict__ h1,
                                             uint4* __restrict__ bits4,
                                             half8* __restrict__ Btab,
                                             int* __restrict__ dsti, int n_total) {
    __shared__ int lm[256 * 27];  // 27.6 KB
    const int tid = threadIdx.x;
    const int n0 = blockIdx.x * 256;
    const int n = n0 + tid;

    // fused scat_max: issue early so atomic latency hides under mask staging
    if (n < n_total) atomicMax(dsti + cell_of(coords, batch, n), n + 1);

    if (blockIdx.x < NS && tid < 64) {   // build Btab (tiny, folded in)
        int s = blockIdx.x, q = tid >> 4, d = tid & 15;
        int kk = 4 * s + q;
        half8 b;
#pragma unroll
        for (int j = 0; j < CH; j++)
            b[j] = (d < CH && kk < KK) ? (_Float16)w2[(kk * CH + j) * CH + d]
                                       : (_Float16)0.f;
        Btab[s * 64 + tid] = b;
    }
    if (blockIdx.x == 0 && tid == 0) {   // keep sentinel row zeroed (insurance)
        half8 z;
#pragma unroll
        for (int c = 0; c < CH; c++) z[c] = (_Float16)0.f;
        h1[n_total] = z;
    }

    float acc[CH] = {0.f, 0.f, 0.f, 0.f, 0.f, 0.f, 0.f, 0.f};
    unsigned cb[3];
#pragma unroll
    for (int ch = 0; ch < 3; ch++) {
        // stage 27-k chunk, flat coalesced (proven strided pattern)
#pragma unroll
        for (int j = 0; j < 27; j++) {
            int i = tid + j * 256;
            int r = i / 27, c = i - r * 27;
            int srcn = n0 + r; if (srcn >= n_total) srcn = n_total - 1;
            lm[i] = nbr_mask[(long)srcn * KK + ch * 27 + c];
        }
        __syncthreads();
        unsigned cbits = 0;
        const int* row = lm + tid * 27;   // bank stride 27 -> 2-way, free
#pragma unroll
        for (int kk = 0; kk < 27; kk++) {
            int m = row[kk];
            cbits |= (unsigned)(m & 1) << kk;
            float fm = (float)m;
            const float* wp = w1 + (ch * 27 + kk) * CH;  // wave-uniform s_load
#pragma unroll
            for (int c = 0; c < CH; c++) acc[c] += fm * wp[c];
        }
        cb[ch] = cbits;
        __syncthreads();
    }

    if (n < n_total) {
        half8 r;
#pragma unroll
        for (int c = 0; c < CH; c++) r[c] = (_Float16)fmaxf(acc[c], 0.f);
        h1[n] = r;
        uint4 bw;
        bw.x = cb[0] | (cb[1] << 27);
        bw.y = (cb[1] >> 5) | (cb[2] << 22);
        bw.z = cb[2] >> 10;
        bw.w = 0u;
        bits4[n] = bw;
    }
}

// ---------------- layer 2 + head + scat_write fusion ------------------------
// Block = 256 thr = 4 waves; wave owns 16 rows. Wave-private idx staging in
// LDS (contiguous 5184 B via dwordx4), block-shared Btab in LDS. Gathers are
// EXEC-MASKED: bit=0 lanes issue no vmem request (~50% of lanes).
// Epilogue: m==0 lanes hold the 4 output scalars -> write winner cells
// directly into the dense grid (dsti election done by k_h1b).
__global__ __launch_bounds__(256, 4) void k_h2m(const half8* __restrict__ h1,
                                                const half8* __restrict__ Btab,
                                                const int* __restrict__ nbr_idx,
                                                const uint4* __restrict__ bits4,
                                                const float* __restrict__ w_out,
                                                const int* __restrict__ coords,
                                                const int* __restrict__ batch,
                                                float* __restrict__ dstf,
                                                int n_total) {
    __shared__ int4 sB[NS * 64];        // 21504 B Btab copy
    __shared__ int  sidx[4 * 1300];     // 4 waves x (1296 idx + pad) = 20800 B
    const int tid = threadIdx.x;
    const int lane = tid & 63, wid = tid >> 6;
    const int m = lane & 15, q = lane >> 4;

    const int rw = blockIdx.x * 64 + (wid << 4);       // wave's first row
    int wb = rw;
    if (wb + 16 > n_total) wb = n_total - 16;          // clamp (N%16==0)

    // stage wave's 16 idx rows: 5184 contiguous bytes = 324 int4
    {
        int4* dst = (int4*)(sidx + wid * 1300);
        const int4* gsrc = (const int4*)(nbr_idx + (size_t)wb * KK);
#pragma unroll
        for (int j = 0; j < 6; j++) {
            int li = lane + j * 64;
            if (li < 324) dst[li] = gsrc[li];
        }
    }
    // stage Btab: 1344 int4, block-wide
    {
        const int4* gB = (const int4*)Btab;
#pragma unroll
        for (int j = 0; j < 6; j++) {
            int i = tid + j * 256;
            if (i < NS * 64) sB[i] = gB[i];
        }
    }
    __syncthreads();

    const int rowc = wb + m;
    const uint4 bw = bits4[rowc];
    const int* mi = sidx + wid * 1300 + m * KK + q;    // [4s] per slice

    f32x4 acc0 = {0.f, 0.f, 0.f, 0.f};
    f32x4 acc1 = {0.f, 0.f, 0.f, 0.f};
#pragma unroll
    for (int s = 0; s < NS; s++) {
        const unsigned word = (s < 8) ? bw.x : (s < 16) ? bw.y : bw.z;
        const unsigned bit = (word >> ((4 * s + q) & 31)) & 1u;
        // s==20, q>=1 reads pad garbage; bit==0 there (bits 81+ zero) so the
        // exec mask kills both the load and the contribution. No OOB: 1298<1300.
        const unsigned ixr = (unsigned)mi[4 * s];      // ds_read_b32, imm offset
        half8 a = {(_Float16)0.f, (_Float16)0.f, (_Float16)0.f, (_Float16)0.f,
                   (_Float16)0.f, (_Float16)0.f, (_Float16)0.f, (_Float16)0.f};
        if (bit) a = h1[ixr];                          // exec-masked 16 B gather
        half8 b = *(const half8*)&sB[s * 64 + lane];   // ds_read_b128
        if (s & 1) acc1 = __builtin_amdgcn_mfma_f32_16x16x32_f16(a, b, acc1, 0, 0, 0);
        else       acc0 = __builtin_amdgcn_mfma_f32_16x16x32_f16(a, b, acc0, 0, 0, 0);
    }
    f32x4 acc = acc0 + acc1;

    // C/D layout: col = lane&15 (=channel m), row = q*4 + reg (=local out row).
    // Reduce over channels (relu * w_out) via 16-lane shuffle over m.
    float wo = (m < CH) ? w_out[m] : 0.f;
    float v0 = fmaxf(acc[0], 0.f) * wo, v1 = fmaxf(acc[1], 0.f) * wo;
    float v2 = fmaxf(acc[2], 0.f) * wo, v3 = fmaxf(acc[3], 0.f) * wo;
#pragma unroll
    for (int off = 1; off < 16; off <<= 1) {
        v0 += __shfl_xor(v0, off, 16);
        v1 += __shfl_xor(v1, off, 16);
        v2 += __shfl_xor(v2, off, 16);
        v3 += __shfl_xor(v3, off, 16);
    }
    if (m == 0) {
        // fused scat_write: rw-based rows (tail-wave gn >= n_total -> no-op).
        // dsti aliasing dstf is the pre-existing proven pattern: winner's
        // float bits can never collide with a valid n+1 (<2^18; float bits of
        // any nonzero output are >=~0x30000000, zero is 0).
        const int* dsti = (const int*)dstf;
        int gn = rw + q * 4;
        if (gn + 0 < n_total) { int c0 = cell_of(coords, batch, gn + 0);
                                if (dsti[c0] == gn + 1) dstf[c0] = v0; }
        if (gn + 1 < n_total) { int c1 = cell_of(coords, batch, gn + 1);
                                if (dsti[c1] == gn + 2) dstf[c1] = v1; }
        if (gn + 2 < n_total) { int c2 = cell_of(coords, batch, gn + 2);
                                if (dsti[c2] == gn + 3) dstf[c2] = v2; }
        if (gn + 3 < n_total) { int c3 = cell_of(coords, batch, gn + 3);
                                if (dsti[c3] == gn + 4) dstf[c3] = v3; }
    }
}

extern "C" void kernel_launch(void* const* d_in, const int* in_sizes, int n_in,
                              void* d_out, int out_size, void* d_ws, size_t ws_size,
                              hipStream_t stream) {
    const float* w1       = (const float*)d_in[1];
    const float* w2       = (const float*)d_in[2];
    const float* w_out    = (const float*)d_in[3];
    const int*   nbr_idx  = (const int*)d_in[4];
    const int*   nbr_mask = (const int*)d_in[5];
    const int*   coords   = (const int*)d_in[6];
    const int*   batch    = (const int*)d_in[7];

    int n_total = in_sizes[0];

    // ws: h1 (N+1 fp16x8) | bits4 (N uint4) | Btab (21.5 KB)
    half8* h1    = (half8*)d_ws;
    uint4* bits4 = (uint4*)((char*)d_ws + (size_t)(n_total + 1) * sizeof(half8));
    half8* Btab  = (half8*)((char*)bits4 + (size_t)n_total * sizeof(uint4));
    float* out   = (float*)d_out;

    hipMemsetAsync(out, 0, (size_t)out_size * sizeof(float), stream);

    int nb = (n_total + 255) / 256;
    k_h1b<<<nb, 256, 0, stream>>>(w1, w2, nbr_mask, coords, batch,
                                  h1, bits4, Btab, (int*)out, n_total);
    int nb2 = (n_total + 63) / 64;
    k_h2m<<<nb2, 256, 0, stream>>>(h1, Btab, nbr_idx, bits4, w_out,
                                   coords, batch, out, n_total);
}

// Round 8
// 207.402 us; speedup vs baseline: 1.0676x; 1.0676x over previous
//
#include <hip/hip_runtime.h>
#include <hip/hip_fp16.h>

// SparseEncoder4D: gather-GEMM-scatter sparse conv (1->8->8->1) + dense scatter.
// Slot model (R10-R12): k_h2m cost ~ vmem lane-slots/wave x waves/CU, with a
// latency-exposure residual that shrinks with occupancy.
// R13 post-mortem: scat_write fusion into k_h2m regressed it 46.5->68.5 us
// (FETCH +23 MB, WRITE +4 MB: random dsti reads + grid writes in the epilogue
// at 26% occupancy). Dispatch overhead measured ~5 us/dispatch (non-h2m only
// -10 us for 2 fewer dispatches). Exec-mask gather kept (halves gather slots).
// R14: revert scat_write fusion (restore outf + k_scat_write); keep scat_max
// in k_h1b. Occupancy fix: sB stored compact (cols d<8 only, zeros for m>=8
// synthesized) -> LDS 42.5->31.5 KB -> 5 blocks/CU (~60% occ).
// Slot budget ~1320/wave -> predict k_h2m 28-32 us, total 185-195 us.
// R15: byte-identical resubmission of R14 (container infra failure, no data).
// NOTE: assumes n_total % 16 == 0 (holds: 150000).

#define KK 81
#define CH 8
#define NS 21     // K-slices of 32: ceil(648/32)
#define TT 4
#define ZZ 32
#define YY 256
#define XX 256

typedef __attribute__((ext_vector_type(8))) _Float16 half8;  // 16 B
typedef __attribute__((ext_vector_type(4))) float f32x4;

__device__ __forceinline__ int cell_of(const int* coords, const int* batch, int n) {
    int4 c = *(const int4*)(coords + 4 * n);  // (x, y, z, t)
    int b = batch[n];
    return (((b * TT + c.w) * ZZ + c.z) * YY + c.y) * XX + c.x;
}

// ---------------- layer 1 (feats==ones) + scat_max fusion -------------------
// h1 fp16, bits4[n]={w0,w1,w2,0} (81-bit mask LE), Btab8 (compact B-frags:
// Btab8[s*32+q*8+d] = fragment for slice s, k-quad q, out-channel d<8), and
// atomicMax winner-election into the dense grid (out as int).
__global__ __launch_bounds__(256) void k_h1b(const float* __restrict__ w1,
                                             const float* __restrict__ w2,
                                             const int* __restrict__ nbr_mask,
                                             const int* __restrict__ coords,
                                             const int* __restrict__ batch,
                                             half8* __restrict__ h1,
                                             uint4* __restrict__ bits4,
                                             half8* __restrict__ Btab8,
                                             int* __restrict__ dsti, int n_total) {
    __shared__ int lm[256 * 27];  // 27.6 KB
    const int tid = threadIdx.x;
    const int n0 = blockIdx.x * 256;
    const int n = n0 + tid;

    // fused scat_max: issue early so atomic latency hides under mask staging
    if (n < n_total) atomicMax(dsti + cell_of(coords, batch, n), n + 1);

    if (blockIdx.x < NS && tid < 32) {   // build compact Btab8 (d<8 only)
        int s = blockIdx.x, q = tid >> 3, d = tid & 7;
        int kk = 4 * s + q;
        half8 b;
#pragma unroll
        for (int j = 0; j < CH; j++)
            b[j] = (kk < KK) ? (_Float16)w2[(kk * CH + j) * CH + d]
                             : (_Float16)0.f;
        Btab8[s * 32 + tid] = b;
    }

    float acc[CH] = {0.f, 0.f, 0.f, 0.f, 0.f, 0.f, 0.f, 0.f};
    unsigned cb[3];
#pragma unroll
    for (int ch = 0; ch < 3; ch++) {
        // stage 27-k chunk, flat coalesced (proven strided pattern)
#pragma unroll
        for (int j = 0; j < 27; j++) {
            int i = tid + j * 256;
            int r = i / 27, c = i - r * 27;
            int srcn = n0 + r; if (srcn >= n_total) srcn = n_total - 1;
            lm[i] = nbr_mask[(long)srcn * KK + ch * 27 + c];
        }
        __syncthreads();
        unsigned cbits = 0;
        const int* row = lm + tid * 27;   // bank stride 27 -> 2-way, free
#pragma unroll
        for (int kk = 0; kk < 27; kk++) {
            int m = row[kk];
            cbits |= (unsigned)(m & 1) << kk;
            float fm = (float)m;
            const float* wp = w1 + (ch * 27 + kk) * CH;  // wave-uniform s_load
#pragma unroll
            for (int c = 0; c < CH; c++) acc[c] += fm * wp[c];
        }
        cb[ch] = cbits;
        __syncthreads();
    }

    if (n < n_total) {
        half8 r;
#pragma unroll
        for (int c = 0; c < CH; c++) r[c] = (_Float16)fmaxf(acc[c], 0.f);
        h1[n] = r;
        uint4 bw;
        bw.x = cb[0] | (cb[1] << 27);
        bw.y = (cb[1] >> 5) | (cb[2] << 22);
        bw.z = cb[2] >> 10;
        bw.w = 0u;
        bits4[n] = bw;
    }
}

// ---------------- layer 2 + head: MFMA gather-GEMM --------------------------
// Block = 256 thr = 4 waves; wave owns 16 rows. Wave-private idx staging in
// LDS (contiguous 5184 B via dwordx4), compact Btab8 (10.75 KB) block-shared.
// LDS total 31.5 KB -> 5 blocks/CU. Gathers are EXEC-MASKED: bit=0 lanes
// issue no vmem request (~50% density). Lanes m>=8 use a zero B-fragment
// (structurally zero columns; epilogue wo=0 double-guards them).
__global__ __launch_bounds__(256, 4) void k_h2m(const half8* __restrict__ h1,
                                                const half8* __restrict__ Btab8,
                                                const int* __restrict__ nbr_idx,
                                                const uint4* __restrict__ bits4,
                                                const float* __restrict__ w_out,
                                                float* __restrict__ outf,
                                                int n_total) {
    __shared__ int4 sB8[NS * 32];       // 10752 B compact Btab
    __shared__ int  sidx[4 * 1300];     // 4 waves x (1296 idx + pad) = 20800 B
    const int tid = threadIdx.x;
    const int lane = tid & 63, wid = tid >> 6;
    const int m = lane & 15, q = lane >> 4;

    const int rw = blockIdx.x * 64 + (wid << 4);       // wave's first row
    int wb = rw;
    if (wb + 16 > n_total) wb = n_total - 16;          // clamp (N%16==0)

    // stage wave's 16 idx rows: 5184 contiguous bytes = 324 int4
    {
        int4* dst = (int4*)(sidx + wid * 1300);
        const int4* gsrc = (const int4*)(nbr_idx + (size_t)wb * KK);
#pragma unroll
        for (int j = 0; j < 6; j++) {
            int li = lane + j * 64;
            if (li < 324) dst[li] = gsrc[li];
        }
    }
    // stage compact Btab8: 672 int4, block-wide
    {
        const int4* gB = (const int4*)Btab8;
#pragma unroll
        for (int j = 0; j < 3; j++) {
            int i = tid + j * 256;
            if (i < NS * 32) sB8[i] = gB[i];
        }
    }
    __syncthreads();

    const int rowc = wb + m;
    const uint4 bw = bits4[rowc];
    const int* mi = sidx + wid * 1300 + m * KK + q;    // [4s] per slice

    f32x4 acc0 = {0.f, 0.f, 0.f, 0.f};
    f32x4 acc1 = {0.f, 0.f, 0.f, 0.f};
#pragma unroll
    for (int s = 0; s < NS; s++) {
        const unsigned word = (s < 8) ? bw.x : (s < 16) ? bw.y : bw.z;
        const unsigned bit = (word >> ((4 * s + q) & 31)) & 1u;
        // s==20, q>=1 reads pad garbage; bit==0 there (bits 81+ zero) so the
        // exec mask kills both the load and the contribution. No OOB: 1298<1300.
        const unsigned ixr = (unsigned)mi[4 * s];      // ds_read_b32, imm offset
        half8 a = {(_Float16)0.f, (_Float16)0.f, (_Float16)0.f, (_Float16)0.f,
                   (_Float16)0.f, (_Float16)0.f, (_Float16)0.f, (_Float16)0.f};
        if (bit) a = h1[ixr];                          // exec-masked 16 B gather
        half8 b = {(_Float16)0.f, (_Float16)0.f, (_Float16)0.f, (_Float16)0.f,
                   (_Float16)0.f, (_Float16)0.f, (_Float16)0.f, (_Float16)0.f};
        if (m < CH) b = *(const half8*)&sB8[s * 32 + q * 8 + m];  // ds_read_b128
        if (s & 1) acc1 = __builtin_amdgcn_mfma_f32_16x16x32_f16(a, b, acc1, 0, 0, 0);
        else       acc0 = __builtin_amdgcn_mfma_f32_16x16x32_f16(a, b, acc0, 0, 0, 0);
    }
    f32x4 acc = acc0 + acc1;

    // C/D layout: col = lane&15 (=channel m), row = q*4 + reg (=local out row).
    // Reduce over channels (relu * w_out) via 16-lane shuffle over m.
    float wo = (m < CH) ? w_out[m] : 0.f;
    float v0 = fmaxf(acc[0], 0.f) * wo, v1 = fmaxf(acc[1], 0.f) * wo;
    float v2 = fmaxf(acc[2], 0.f) * wo, v3 = fmaxf(acc[3], 0.f) * wo;
#pragma unroll
    for (int off = 1; off < 16; off <<= 1) {
        v0 += __shfl_xor(v0, off, 16);
        v1 += __shfl_xor(v1, off, 16);
        v2 += __shfl_xor(v2, off, 16);
        v3 += __shfl_xor(v3, off, 16);
    }
    if (m == 0) {
        // rw-based: tail-wave rows (wb!=rw) have gn >= n_total -> no-op.
        int gn = rw + q * 4;
        if (gn + 0 < n_total) outf[gn + 0] = v0;
        if (gn + 1 < n_total) outf[gn + 1] = v1;
        if (gn + 2 < n_total) outf[gn + 2] = v2;
        if (gn + 3 < n_total) outf[gn + 3] = v3;
    }
}

// ---------------- deterministic dense scatter (write phase) -----------------
__global__ __launch_bounds__(256) void k_scat_write(const int* __restrict__ coords,
                                                    const int* __restrict__ batch,
                                                    const float* __restrict__ outf,
                                                    int* dsti, float* dstf, int n_total) {
    int n = blockIdx.x * blockDim.x + threadIdx.x;
    if (n >= n_total) return;
    int cell = cell_of(coords, batch, n);
    if (dsti[cell] == n + 1) dstf[cell] = outf[n];
}

extern "C" void kernel_launch(void* const* d_in, const int* in_sizes, int n_in,
                              void* d_out, int out_size, void* d_ws, size_t ws_size,
                              hipStream_t stream) {
    const float* w1       = (const float*)d_in[1];
    const float* w2       = (const float*)d_in[2];
    const float* w_out    = (const float*)d_in[3];
    const int*   nbr_idx  = (const int*)d_in[4];
    const int*   nbr_mask = (const int*)d_in[5];
    const int*   coords   = (const int*)d_in[6];
    const int*   batch    = (const int*)d_in[7];

    int n_total = in_sizes[0];

    // ws: h1 (N+1 fp16x8) | bits4 (N uint4) | outf (N f32) | Btab8 (10.75 KB)
    half8* h1    = (half8*)d_ws;
    uint4* bits4 = (uint4*)((char*)d_ws + (size_t)(n_total + 1) * sizeof(half8));
    float* outf  = (float*)((char*)bits4 + (size_t)n_total * sizeof(uint4));
    half8* Btab8 = (half8*)(outf + n_total);
    float* out   = (float*)d_out;

    hipMemsetAsync(out, 0, (size_t)out_size * sizeof(float), stream);

    int nb = (n_total + 255) / 256;
    k_h1b<<<nb, 256, 0, stream>>>(w1, w2, nbr_mask, coords, batch,
                                  h1, bits4, Btab8, (int*)out, n_total);
    int nb2 = (n_total + 63) / 64;
    k_h2m<<<nb2, 256, 0, stream>>>(h1, Btab8, nbr_idx, bits4, w_out, outf, n_total);
    k_scat_write<<<nb, 256, 0, stream>>>(coords, batch, outf, (int*)out, out, n_total);
}

// Round 9
// 203.883 us; speedup vs baseline: 1.0860x; 1.0173x over previous
//
#include <hip/hip_runtime.h>
#include <hip/hip_fp16.h>

// SparseEncoder4D: gather-GEMM-scatter sparse conv (1->8->8->1) + dense scatter.
// R14/15 post-mortem: k_h2m stuck ~47-50 us across occupancy 26->45% and
// gather masking changes -> cost = distinct-cache-line service (~6.1M random
// 64B lines), not lane slots. Leave k_h2m. The ~158 us invisible block is real
// work (R13: removing 2 dispatches saved only ~7 us): SDMA memset (never in
// dispatch table -> not a kernel; SDMA blit BW is poor) + k_h1b (40-48 us vs
// ~12 us floor; 5184 scalar FMAs/wave on a matmul-shaped op).
// R16: (a) k_zero kernel replaces hipMemsetAsync: float4 grid-stride, 2048
//          blocks, ~67 MB at ~5-6 TB/s ~= 13 us, and VISIBLE in counters.
//          Also builds W1tab (w1 in B-frag layout) + h1 sentinel.
//      (b) k_h1b rewritten as mask-GEMM MFMA: h1 = mask(Nx81) x w1(81x8),
//          3 mfma_16x16x32_f16 per wave replace 5184 VALU FMAs. Masks stage
//          coalesced (5184 contiguous ints/block via int4). Bits pack via
//          per-slice bytes + 2 shfl_xor (direct 81-bit LE words).
// Predict k_h1b ~12-16 us, total 207 -> ~130-150 us.
// NOTE: assumes n_total >= 64 and n_total % 16 == 0 (holds: 150000).

#define KK 81
#define CH 8
#define NS 21     // K-slices of 32 for k_h2m: ceil(648/32)
#define TT 4
#define ZZ 32
#define YY 256
#define XX 256

typedef __attribute__((ext_vector_type(8))) _Float16 half8;  // 16 B
typedef __attribute__((ext_vector_type(4))) float f32x4;

__device__ __forceinline__ int cell_of(const int* coords, const int* batch, int n) {
    int4 c = *(const int4*)(coords + 4 * n);  // (x, y, z, t)
    int b = batch[n];
    return (((b * TT + c.w) * ZZ + c.z) * YY + c.y) * XX + c.x;
}

// ---------------- k_zero: grid zero + W1tab build + sentinel ----------------
// W1tab[s*64+l] = B-fragment of w1 for slice s (K=32s+8(l>>4)+j), col d=l&15;
// zero for K>=81 or d>=8 (same convention as Btab8 -> garbage A rows * 0 = 0).
__global__ __launch_bounds__(256) void k_zero(float4* __restrict__ dst, int n4,
                                              const float* __restrict__ w1,
                                              half8* __restrict__ W1tab,
                                              half8* __restrict__ h1, int n_total) {
    const int tid = threadIdx.x;
    if (blockIdx.x == 0) {
        if (tid < 192) {
            int s = tid >> 6, l = tid & 63, qb = (l >> 4) & 3, d = l & 15;
            half8 b;
#pragma unroll
            for (int j = 0; j < 8; j++) {
                int k = 32 * s + 8 * qb + j;
                b[j] = (k < KK && d < CH) ? (_Float16)w1[k * CH + d] : (_Float16)0.f;
            }
            W1tab[s * 64 + l] = b;
        }
        if (tid == 0) {
            half8 z;
#pragma unroll
            for (int c = 0; c < CH; c++) z[c] = (_Float16)0.f;
            h1[n_total] = z;  // sentinel row (insurance)
        }
    }
    float4 zz = {0.f, 0.f, 0.f, 0.f};
    for (int i = blockIdx.x * 256 + tid; i < n4; i += gridDim.x * 256) dst[i] = zz;
}

// ---------------- layer 1 as mask-GEMM MFMA + scat_max fusion ---------------
// Block = 256 thr = 4 waves, covers 64 rows (wave w: rows wb+16w..wb+16w+15).
// Stage 64x81 mask ints (5184 contiguous) via int4. Lane (m,q): A-frag for
// row lr=16w+m, K=32s+8q+j from staged ints (bit-select to fp16 1.0/0.0 --
// garbage beyond k=80 becomes 0/1, killed by zero W1tab rows). 3 MFMAs.
// Bits: byte_s per lane -> word_s = OR over q of byte<<8q via 2 shfl_xor;
// words ARE the 81-bit LE packing k_h2m consumes. Btab8 build + atomicMax kept.
__global__ __launch_bounds__(256) void k_h1b(const half8* __restrict__ W1tab,
                                             const float* __restrict__ w2,
                                             const int* __restrict__ nbr_mask,
                                             const int* __restrict__ coords,
                                             const int* __restrict__ batch,
                                             half8* __restrict__ h1,
                                             uint4* __restrict__ bits4,
                                             half8* __restrict__ Btab8,
                                             int* __restrict__ dsti, int n_total) {
    __shared__ int sm[5200];   // 64*81 = 5184 + pad for s=2 tail reads (20.8 KB)
    const int tid = threadIdx.x;
    const int lane = tid & 63, wid = tid >> 6;
    const int m = lane & 15, q = lane >> 4;
    const int n0 = blockIdx.x * 64;
    int wb = n0;
    if (wb + 64 > n_total) wb = n_total - 64;   // overlap tail; rewrites identical

    // fused scat_max: issue early, latency hides under staging
    if (tid < 64) atomicMax(dsti + cell_of(coords, batch, wb + tid), wb + tid + 1);

    if (blockIdx.x < NS && tid < 32) {   // build compact Btab8 (d<8 only)
        int s = blockIdx.x, qb = tid >> 3, d = tid & 7;
        int kk = 4 * s + qb;
        half8 b;
#pragma unroll
        for (int j = 0; j < CH; j++)
            b[j] = (kk < KK) ? (_Float16)w2[(kk * CH + j) * CH + d]
                             : (_Float16)0.f;
        Btab8[s * 32 + tid] = b;
    }

    // stage 5184 contiguous mask ints = 1296 int4 (wb*81 is 16B-aligned)
    const int4* msrc = (const int4*)(nbr_mask + (size_t)wb * KK);
#pragma unroll
    for (int j = 0; j < 6; j++) {
        int i = tid + j * 256;
        if (i < 1296) ((int4*)sm)[i] = msrc[i];
    }
    __syncthreads();

    const int lr = wid * 16 + m;
    f32x4 acc = {0.f, 0.f, 0.f, 0.f};
    unsigned wv[3];
#pragma unroll
    for (int s = 0; s < 3; s++) {
        const int base = lr * KK + 32 * s + 8 * q;   // max 5191+7=5198 < 5200
        int mm[8];
#pragma unroll
        for (int j = 0; j < 8; j++) mm[j] = sm[base + j] & 1;
        unsigned byte = 0;
#pragma unroll
        for (int j = 0; j < 8; j++) byte |= (unsigned)mm[j] << j;
        if (s == 2) byte &= (q < 2) ? 0xFFu : (q == 2 ? 0x1u : 0x0u);  // k>80 off
        union { unsigned u[4]; half8 h; } ua;
#pragma unroll
        for (int jj = 0; jj < 4; jj++)
            ua.u[jj] = (unsigned)mm[2 * jj] * 0x3C00u |
                       ((unsigned)mm[2 * jj + 1] * 0x3C00u << 16);
        half8 bfrag = W1tab[s * 64 + lane];          // L1-hot 3 KB
        acc = __builtin_amdgcn_mfma_f32_16x16x32_f16(ua.h, bfrag, acc, 0, 0, 0);
        unsigned v = byte << (8 * q);
        v |= __shfl_xor(v, 16);                      // OR across the 4 q-lanes
        v |= __shfl_xor(v, 32);
        wv[s] = v;
    }
    wv[2] &= 0x1FFFFu;   // bits 64..80 only

    if (q == 0) {        // lanes 0..15: one uint4 per row, contiguous 256 B
        uint4 bwout; bwout.x = wv[0]; bwout.y = wv[1]; bwout.z = wv[2]; bwout.w = 0u;
        bits4[wb + wid * 16 + m] = bwout;
    }

    // D layout: col = lane&15 (=channel), row = q*4 + reg (=local row).
    if (m < CH) {
        _Float16* hp = (_Float16*)h1;
#pragma unroll
        for (int r = 0; r < 4; r++) {
            float f = fmaxf(acc[r], 0.f);
            hp[(size_t)(wb + wid * 16 + q * 4 + r) * CH + m] = (_Float16)f;
        }
    }
}

// ---------------- layer 2 + head: MFMA gather-GEMM (unchanged R14) ----------
__global__ __launch_bounds__(256, 4) void k_h2m(const half8* __restrict__ h1,
                                                const half8* __restrict__ Btab8,
                                                const int* __restrict__ nbr_idx,
                                                const uint4* __restrict__ bits4,
                                                const float* __restrict__ w_out,
                                                float* __restrict__ outf,
                                                int n_total) {
    __shared__ int4 sB8[NS * 32];       // 10752 B compact Btab
    __shared__ int  sidx[4 * 1300];     // 4 waves x (1296 idx + pad) = 20800 B
    const int tid = threadIdx.x;
    const int lane = tid & 63, wid = tid >> 6;
    const int m = lane & 15, q = lane >> 4;

    const int rw = blockIdx.x * 64 + (wid << 4);       // wave's first row
    int wb = rw;
    if (wb + 16 > n_total) wb = n_total - 16;          // clamp (N%16==0)

    // stage wave's 16 idx rows: 5184 contiguous bytes = 324 int4
    {
        int4* dst = (int4*)(sidx + wid * 1300);
        const int4* gsrc = (const int4*)(nbr_idx + (size_t)wb * KK);
#pragma unroll
        for (int j = 0; j < 6; j++) {
            int li = lane + j * 64;
            if (li < 324) dst[li] = gsrc[li];
        }
    }
    // stage compact Btab8: 672 int4, block-wide
    {
        const int4* gB = (const int4*)Btab8;
#pragma unroll
        for (int j = 0; j < 3; j++) {
            int i = tid + j * 256;
            if (i < NS * 32) sB8[i] = gB[i];
        }
    }
    __syncthreads();

    const int rowc = wb + m;
    const uint4 bw = bits4[rowc];
    const int* mi = sidx + wid * 1300 + m * KK + q;    // [4s] per slice

    f32x4 acc0 = {0.f, 0.f, 0.f, 0.f};
    f32x4 acc1 = {0.f, 0.f, 0.f, 0.f};
#pragma unroll
    for (int s = 0; s < NS; s++) {
        const unsigned word = (s < 8) ? bw.x : (s < 16) ? bw.y : bw.z;
        const unsigned bit = (word >> ((4 * s + q) & 31)) & 1u;
        const unsigned ixr = (unsigned)mi[4 * s];      // ds_read_b32, imm offset
        half8 a = {(_Float16)0.f, (_Float16)0.f, (_Float16)0.f, (_Float16)0.f,
                   (_Float16)0.f, (_Float16)0.f, (_Float16)0.f, (_Float16)0.f};
        if (bit) a = h1[ixr];                          // exec-masked 16 B gather
        half8 b = {(_Float16)0.f, (_Float16)0.f, (_Float16)0.f, (_Float16)0.f,
                   (_Float16)0.f, (_Float16)0.f, (_Float16)0.f, (_Float16)0.f};
        if (m < CH) b = *(const half8*)&sB8[s * 32 + q * 8 + m];  // ds_read_b128
        if (s & 1) acc1 = __builtin_amdgcn_mfma_f32_16x16x32_f16(a, b, acc1, 0, 0, 0);
        else       acc0 = __builtin_amdgcn_mfma_f32_16x16x32_f16(a, b, acc0, 0, 0, 0);
    }
    f32x4 acc = acc0 + acc1;

    float wo = (m < CH) ? w_out[m] : 0.f;
    float v0 = fmaxf(acc[0], 0.f) * wo, v1 = fmaxf(acc[1], 0.f) * wo;
    float v2 = fmaxf(acc[2], 0.f) * wo, v3 = fmaxf(acc[3], 0.f) * wo;
#pragma unroll
    for (int off = 1; off < 16; off <<= 1) {
        v0 += __shfl_xor(v0, off, 16);
        v1 += __shfl_xor(v1, off, 16);
        v2 += __shfl_xor(v2, off, 16);
        v3 += __shfl_xor(v3, off, 16);
    }
    if (m == 0) {
        int gn = rw + q * 4;   // tail-wave rows (wb!=rw) -> gn >= n_total -> no-op
        if (gn + 0 < n_total) outf[gn + 0] = v0;
        if (gn + 1 < n_total) outf[gn + 1] = v1;
        if (gn + 2 < n_total) outf[gn + 2] = v2;
        if (gn + 3 < n_total) outf[gn + 3] = v3;
    }
}

// ---------------- deterministic dense scatter (write phase) -----------------
__global__ __launch_bounds__(256) void k_scat_write(const int* __restrict__ coords,
                                                    const int* __restrict__ batch,
                                                    const float* __restrict__ outf,
                                                    int* dsti, float* dstf, int n_total) {
    int n = blockIdx.x * blockDim.x + threadIdx.x;
    if (n >= n_total) return;
    int cell = cell_of(coords, batch, n);
    if (dsti[cell] == n + 1) dstf[cell] = outf[n];
}

extern "C" void kernel_launch(void* const* d_in, const int* in_sizes, int n_in,
                              void* d_out, int out_size, void* d_ws, size_t ws_size,
                              hipStream_t stream) {
    const float* w1       = (const float*)d_in[1];
    const float* w2       = (const float*)d_in[2];
    const float* w_out    = (const float*)d_in[3];
    const int*   nbr_idx  = (const int*)d_in[4];
    const int*   nbr_mask = (const int*)d_in[5];
    const int*   coords   = (const int*)d_in[6];
    const int*   batch    = (const int*)d_in[7];

    int n_total = in_sizes[0];

    // ws: h1 (N+1 fp16x8) | bits4 (N uint4) | outf (N f32) | Btab8 | W1tab
    half8* h1    = (half8*)d_ws;
    uint4* bits4 = (uint4*)((char*)d_ws + (size_t)(n_total + 1) * sizeof(half8));
    float* outf  = (float*)((char*)bits4 + (size_t)n_total * sizeof(uint4));
    half8* Btab8 = (half8*)(outf + n_total);
    half8* W1tab = Btab8 + NS * 32;
    float* out   = (float*)d_out;

    int n4 = out_size / 4;   // 16,777,216 floats -> 4,194,304 float4
    k_zero<<<2048, 256, 0, stream>>>((float4*)out, n4, w1, W1tab, h1, n_total);

    int nb1 = (n_total + 63) / 64;
    k_h1b<<<nb1, 256, 0, stream>>>(W1tab, w2, nbr_mask, coords, batch,
                                   h1, bits4, Btab8, (int*)out, n_total);
    k_h2m<<<nb1, 256, 0, stream>>>(h1, Btab8, nbr_idx, bits4, w_out, outf, n_total);
    int nb = (n_total + 255) / 256;
    k_scat_write<<<nb, 256, 0, stream>>>(coords, batch, outf, (int*)out, out, n_total);
}